// Round 16
// baseline (1034.682 us; speedup 1.0000x reference)
//
#include <hip/hip_runtime.h>

typedef unsigned short ushort_t;
typedef short short8 __attribute__((ext_vector_type(8)));
typedef float f32x4 __attribute__((ext_vector_type(4)));
typedef unsigned short ushort4v __attribute__((ext_vector_type(4)));

#define B_     8
#define L_     2048
#define DMODEL 1024
#define DINNER 2048
#define DSSM   1024
#define H_     4
#define DK_    192
#define DV_    384
#define KEYDIM 768
#define QKLD   1536   // combined q|k row stride
#define VALDIM 1536
#define M_     (B_ * L_)   // 16384

#define MFMA_(a,b,c) __builtin_amdgcn_mfma_f32_16x16x32_bf16(a, b, c, 0, 0, 0)

// ---------- helpers ----------
__device__ __forceinline__ float bf2f(ushort_t u) {
    return __uint_as_float(((unsigned)u) << 16);
}
__device__ __forceinline__ ushort_t f2bf(float f) {
    unsigned x = __float_as_uint(f);
    x += 0x7fffu + ((x >> 16) & 1u);   // RNE
    return (ushort_t)(x >> 16);
}
__device__ __forceinline__ float wsum(float x) {
    #pragma unroll
    for (int m = 1; m < 64; m <<= 1) x += __shfl_xor(x, m, 64);
    return x;
}
__device__ __forceinline__ void gload_lds16(const ushort_t* g, ushort_t* l) {
    __builtin_amdgcn_global_load_lds(
        (const __attribute__((address_space(1))) void*)g,
        (__attribute__((address_space(3))) void*)l, 16, 0, 0);
}

// ---------- zero d_out (fallback when ws too small) ----------
__global__ __launch_bounds__(256)
void k_zero_f32(float* __restrict__ out, int n) {
    int i = blockIdx.x * 256 + threadIdx.x;
    if (i < n) out[i] = 0.f;
}

// ---------- fused prep ----------
__global__ __launch_bounds__(256)
void k_prep(const float* __restrict__ x,
            const float* __restrict__ Win, const float* __restrict__ Wq,
            const float* __restrict__ Wk,  const float* __restrict__ Wv,
            const float* __restrict__ Wg,  const float* __restrict__ Wso,
            const float* __restrict__ Wout,
            ushort_t* __restrict__ x_bf,
            ushort_t* __restrict__ wInT, ushort_t* __restrict__ wQT,
            ushort_t* __restrict__ wKT,  ushort_t* __restrict__ wVT,
            ushort_t* __restrict__ wGT,  ushort_t* __restrict__ wSoBf,
            ushort_t* __restrict__ wOutTopT, ushort_t* __restrict__ wBigT) {
    __shared__ float tile[32][33];
    int id = blockIdx.x;
    if (id < 8192) {
        int i = id * 256 + threadIdx.x;
        const float4* p = (const float4*)(x + (size_t)i * 8);
        float4 a = p[0], b = p[1];
        ushort4v r0 = { f2bf(a.x), f2bf(a.y), f2bf(a.z), f2bf(a.w) };
        ushort4v r1 = { f2bf(b.x), f2bf(b.y), f2bf(b.z), f2bf(b.w) };
        ushort4v* o = (ushort4v*)(x_bf + (size_t)i * 8);
        o[0] = r0; o[1] = r1;
        return;
    }
    id -= 8192;
    if (id < 768) {   // Wso straight convert
        int i = id * 256 + threadIdx.x;
        const float4* p = (const float4*)(Wso + (size_t)i * 8);
        float4 a = p[0], b = p[1];
        ushort4v r0 = { f2bf(a.x), f2bf(a.y), f2bf(a.z), f2bf(a.w) };
        ushort4v r1 = { f2bf(b.x), f2bf(b.y), f2bf(b.z), f2bf(b.w) };
        ushort4v* o = (ushort4v*)(wSoBf + (size_t)i * 8);
        o[0] = r0; o[1] = r1;
        return;
    }
    id -= 768;
    const float* in; ushort_t* outp; int C, nbx, ldout;
    if (id < 2048)                { in = Win;            outp = wInT;        C = 2048; nbx = 64; ldout = 1024; }
    else if ((id -= 2048) < 768)  { in = Wq;             outp = wQT;         C = 768;  nbx = 24; ldout = 1024; }
    else if ((id -= 768) < 768)   { in = Wk;             outp = wKT;         C = 768;  nbx = 24; ldout = 1024; }
    else if ((id -= 768) < 1536)  { in = Wv;             outp = wVT;         C = 1536; nbx = 48; ldout = 1024; }
    else if ((id -= 1536) < 1536) { in = Wg;             outp = wGT;         C = 1536; nbx = 48; ldout = 1024; }
    else if ((id -= 1536) < 1024) { in = Wout;           outp = wOutTopT;    C = 1024; nbx = 32; ldout = 1024; }
    else { id -= 1024;              in = Wout + 1048576; outp = wBigT + 1536; C = 1024; nbx = 32; ldout = 2560; }
    int bx = id % nbx, by = id / nbx;
    int tx = threadIdx.x & 31, ty = threadIdx.x >> 5;   // 32x8
    int c0 = bx * 32, r0 = by * 32;
    #pragma unroll
    for (int i = 0; i < 32; i += 8)
        tile[ty + i][tx] = in[(size_t)(r0 + ty + i) * C + c0 + tx];
    __syncthreads();
    #pragma unroll
    for (int i = 0; i < 32; i += 8)
        outp[(size_t)(c0 + ty + i) * ldout + r0 + tx] = f2bf(tile[tx][ty + i]);
}

// ---------- GEMM: C[M,N] = A[M,K](bf16) * Bt[N,K](bf16), f32 accum ----------
// 128x128 tile, BK=32. B staged via triple-buffered LDS (8KB/buf); A fragments
// loaded DIRECTLY global->registers (double-buffered afA/afB, unroll-by-2) --
// halves LDS read traffic (the measured bottleneck: MfmaUtil 25% @ 8 ds_read
// per 16 MFMA). vmcnt ledger: steady-state queue entering iter t =
// [B(t) 2, A(t) 4, B(t+1) 2] -> vmcnt(2); tail vmcnt(0).
// 1-D grid, XCD-grouped: id == by (mod 8). A panels stay L2-hot per XCD.
// DUAL: virtual K = [A (K1) | A2 (K-K1)].
template<int OUT_BF16, int DUAL>
__global__ __launch_bounds__(256)
void k_gemm(const ushort_t* __restrict__ A, const ushort_t* __restrict__ A2,
            const ushort_t* __restrict__ Bt, void* __restrict__ Cv,
            int N, int K, int K1, int lda, int lda2, int ldb, int ldc) {
    __shared__ ushort_t Bs[3][4096];
    const int t = threadIdx.x;
    const int lane = t & 63, w = t >> 6;
    const int nbx = N >> 7;
    const int id = blockIdx.x;
    const int by = (id & 7) + 8 * ((id >> 3) / nbx);
    const int bx = (id >> 3) % nbx;
    const int m0 = by << 7, n0 = bx << 7;
    const int wm = (w >> 1) << 6, wn = (w & 1) << 6;
    const int fr = lane & 15, kg = lane >> 4;

    f32x4 acc[4][4];
    #pragma unroll
    for (int i = 0; i < 4; ++i)
        #pragma unroll
        for (int j = 0; j < 4; ++j) acc[i][j] = (f32x4){0.f, 0.f, 0.f, 0.f};

    // A-fragment row pointers (per mi), offset kg*8 within the K-step
    const ushort_t* aR[4];
    const ushort_t* cR[4];
    #pragma unroll
    for (int mi = 0; mi < 4; ++mi) {
        int row = m0 + wm + mi * 16 + fr;
        aR[mi] = A + (size_t)row * lda + kg * 8;
        cR[mi] = DUAL ? A2 + (size_t)row * lda2 + kg * 8 : aR[mi];
    }
    // B staging: tile [128][32], thread t -> row t>>2, colgroup (t&3)*8
    const int srow = t >> 2, scol = (t & 3) << 3;
    const ushort_t* b0 = Bt + (size_t)(n0 + srow) * ldb + scol;
    const ushort_t* b1 = b0 + (size_t)64 * ldb;
    const int lof0 = w * 512, lof1 = 2048 + w * 512;

    auto stage = [&](int buf, int kt) {
        gload_lds16(b0 + kt, &Bs[buf][lof0]);
        gload_lds16(b1 + kt, &Bs[buf][lof1]);
    };
    auto loadA = [&](short8 (&af)[4], int kt) {
        if (!DUAL || kt < K1) {
            #pragma unroll
            for (int mi = 0; mi < 4; ++mi) af[mi] = *(const short8*)(aR[mi] + kt);
        } else {
            #pragma unroll
            for (int mi = 0; mi < 4; ++mi) af[mi] = *(const short8*)(cR[mi] + (kt - K1));
        }
    };

    const int NT = K >> 5;
    short8 afA[4], afB[4];
    int bsel = 0;

    auto iter = [&](int tt, short8 (&afC)[4], short8 (&afN)[4]) {
        if (tt + 1 < NT) { asm volatile("s_waitcnt vmcnt(2)" ::: "memory"); }
        else             { asm volatile("s_waitcnt vmcnt(0)" ::: "memory"); }
        __builtin_amdgcn_s_barrier();
        if (tt + 1 < NT) loadA(afN, (tt + 1) << 5);
        if (tt + 2 < NT) {
            int nb = bsel + 2; if (nb >= 3) nb -= 3;
            stage(nb, (tt + 2) << 5);
        }
        // compute(tt) from afC + Bs[bsel]
        short8 bf_[4];
        #pragma unroll
        for (int ni = 0; ni < 4; ++ni)
            bf_[ni] = *(const short8*)&Bs[bsel][(wn + ni * 16 + fr) * 32 + kg * 8];
        #pragma unroll
        for (int mi = 0; mi < 4; ++mi)
            #pragma unroll
            for (int ni = 0; ni < 4; ++ni)
                acc[mi][ni] = MFMA_(afC[mi], bf_[ni], acc[mi][ni]);
        ++bsel; if (bsel == 3) bsel = 0;
    };

    loadA(afA, 0);
    stage(0, 0);
    if (NT > 1) stage(1, 32);
    for (int tt = 0; tt < NT; tt += 2) {
        iter(tt, afA, afB);
        if (tt + 1 < NT) iter(tt + 1, afB, afA);
    }

    const int rbase = m0 + wm + (lane >> 4) * 4;
    const int cbase = n0 + wn + fr;
    #pragma unroll
    for (int mi = 0; mi < 4; ++mi)
        #pragma unroll
        for (int ni = 0; ni < 4; ++ni)
            #pragma unroll
            for (int j = 0; j < 4; ++j) {
                size_t off = (size_t)(rbase + mi * 16 + j) * ldc + cbase + ni * 16;
                if (OUT_BF16) ((ushort_t*)Cv)[off] = f2bf(acc[mi][ni][j]);
                else          ((float*)Cv)[off]    = acc[mi][ni][j];
            }
}

// ---------- depthwise conv (K=4, pad 1/2) + SiLU, rolling-window ----------
#define CONV_LC 16
__global__ __launch_bounds__(256)
void k_conv_silu(const ushort_t* __restrict__ xz,
                 const float* __restrict__ wx, const float* __restrict__ bx,
                 const float* __restrict__ wz, const float* __restrict__ bz,
                 ushort_t* __restrict__ xs, ushort_t* __restrict__ zs) {
    const int blk = blockIdx.x;
    const int b = blk / (L_ / CONV_LC), chunk = blk % (L_ / CONV_LC);
    const int l0 = chunk * CONV_LC;
    const int c4 = threadIdx.x * 4;
    const size_t rowb = (size_t)b * L_;

    float wxv[4][4], wzv[4][4], bxv[4], bzv[4];
    #pragma unroll
    for (int e = 0; e < 4; ++e) {
        bxv[e] = bx[c4 + e]; bzv[e] = bz[c4 + e];
        float4 w1 = *(const float4*)&wx[(c4 + e) * 4];
        float4 w2 = *(const float4*)&wz[(c4 + e) * 4];
        wxv[e][0] = w1.x; wxv[e][1] = w1.y; wxv[e][2] = w1.z; wxv[e][3] = w1.w;
        wzv[e][0] = w2.x; wzv[e][1] = w2.y; wzv[e][2] = w2.z; wzv[e][3] = w2.w;
    }

    auto ldrow = [&](int l, ushort4v& xv, ushort4v& zv) {
        if ((unsigned)l < (unsigned)L_) {
            const ushort_t* p = xz + (rowb + l) * DINNER;
            xv = *(const ushort4v*)&p[c4];
            zv = *(const ushort4v*)&p[1024 + c4];
        } else {
            xv = (ushort4v){0, 0, 0, 0};
            zv = (ushort4v){0, 0, 0, 0};
        }
    };

    ushort4v xa, xb_, xc, xd, za, zb_, zc, zd, xp, zp;
    ldrow(l0 - 1, xa, za);
    ldrow(l0,     xb_, zb_);
    ldrow(l0 + 1, xc, zc);
    ldrow(l0 + 2, xd, zd);

    #pragma unroll
    for (int i = 0; i < CONV_LC; ++i) {
        const int l = l0 + i;
        if (i < CONV_LC - 1) ldrow(l + 3, xp, zp);   // prefetch next window row
        ushort4v ox, oz;
        #pragma unroll
        for (int e = 0; e < 4; ++e) {
            float ax = bxv[e] + wxv[e][0] * bf2f(xa[e]) + wxv[e][1] * bf2f(xb_[e])
                               + wxv[e][2] * bf2f(xc[e]) + wxv[e][3] * bf2f(xd[e]);
            float az = bzv[e] + wzv[e][0] * bf2f(za[e]) + wzv[e][1] * bf2f(zb_[e])
                               + wzv[e][2] * bf2f(zc[e]) + wzv[e][3] * bf2f(zd[e]);
            ox[e] = f2bf(ax / (1.f + expf(-ax)));
            oz[e] = f2bf(az / (1.f + expf(-az)));
        }
        *(ushort4v*)&xs[(rowb + l) * DSSM + c4] = ox;
        *(ushort4v*)&zs[(rowb + l) * DSSM + c4] = oz;
        xa = xb_; xb_ = xc; xc = xd; xd = xp;
        za = zb_; zb_ = zc; zc = zd; zd = zp;
    }
}

// ---------- gk / beta ----------
__global__ __launch_bounds__(256)
void k_gkbeta(const ushort_t* __restrict__ xs, const float* __restrict__ Wgk,
              const float* __restrict__ Wb, const float* __restrict__ bb,
              const float* __restrict__ Alog, const float* __restrict__ dtb,
              float* __restrict__ gk, float* __restrict__ beta) {
    const int w = threadIdx.x >> 6, lane = threadIdx.x & 63;
    const int row = blockIdx.x * 4 + w;
    const ushort_t* xr = xs + (size_t)row * DSSM + lane * 16;
    float sg[4] = {0, 0, 0, 0}, sb[4] = {0, 0, 0, 0};
    #pragma unroll
    for (int i = 0; i < 16; ++i) {
        float xv = bf2f(xr[i]);
        int kk = lane * 16 + i;
        float4 wg  = *(const float4*)&Wgk[kk * 4];
        float4 wb2 = *(const float4*)&Wb[kk * 4];
        sg[0] += xv * wg.x;  sg[1] += xv * wg.y;  sg[2] += xv * wg.z;  sg[3] += xv * wg.w;
        sb[0] += xv * wb2.x; sb[1] += xv * wb2.y; sb[2] += xv * wb2.z; sb[3] += xv * wb2.w;
    }
    #pragma unroll
    for (int h = 0; h < 4; ++h) { sg[h] = wsum(sg[h]); sb[h] = wsum(sb[h]); }
    if (lane < 4) {
        int h = lane;
        int b = row >> 11, l = row & (L_ - 1);
        float xgk = sg[h] + dtb[h];
        float sp = (xgk > 20.f) ? xgk : log1pf(expf(xgk));
        gk[(size_t)(b * 4 + h) * L_ + l] = -expf(Alog[h]) * sp;
        float xb = sb[h] + bb[h];
        beta[(size_t)(b * 4 + h) * L_ + l] = 1.f / (1.f + expf(-xb));
    }
}

// ---------- in-place l2norm over 192-wide groups of qk[M][1536] ----------
__global__ __launch_bounds__(256)
void k_l2norm(ushort_t* __restrict__ x) {
    const int w = threadIdx.x >> 6, lane = threadIdx.x & 63;
    const int idx = blockIdx.x * 4 + w;   // row*8 + group
    const int row = idx >> 3, g = idx & 7;
    ushort_t* p = x + (size_t)row * QKLD + g * DK_;
    float ss = 0.f;
    ushort4v v = {0, 0, 0, 0};
    if (lane < 48) {
        v = *(const ushort4v*)&p[lane * 4];
        #pragma unroll
        for (int e = 0; e < 4; ++e) { float f = bf2f(v[e]); ss += f * f; }
    }
    ss = wsum(ss);
    float r = rsqrtf(ss + 1e-6f);
    if (lane < 48) {
        ushort4v o;
        #pragma unroll
        for (int e = 0; e < 4; ++e) o[e] = f2bf(bf2f(v[e]) * r);
        *(ushort4v*)&p[lane * 4] = o;
    }
}

// ================== chunked gated delta rule ==================
__global__ __launch_bounds__(256)
void k_p1(ushort_t* __restrict__ q, ushort_t* __restrict__ k,
          const float* __restrict__ gkb, const float* __restrict__ beb,
          ushort_t* __restrict__ pbuf, ushort_t* __restrict__ mbuf,
          ushort_t* __restrict__ wneg, float* __restrict__ acb) {
    __shared__ ushort_t KcT[192 * 72];   // [dk][s] raw k transposed
    __shared__ float    Tm[64 * 68];
    __shared__ ushort_t Mw[64 * 72];     // Minv * beta_s * exp(g_s), bf16
    __shared__ float gs[64], bs[64], egq[64], egk[64];

    const int tid = threadIdx.x;
    const int lane = tid & 63, w = tid >> 6;
    const int fr = lane & 15, kg = lane >> 4;
    const int cb = blockIdx.x;           // bh*32 + c
    const int bh = cb >> 5, c = cb & 31;
    const int b = bh >> 2, h = bh & 3;
    const int rb = b * L_ + c * 64;
    const size_t qko = (size_t)rb * QKLD + h * DK_;

    // prefix sums + per-row scale factors (wave 0)
    if (tid < 64) {
        float x = gkb[(size_t)bh * L_ + c * 64 + tid];
        #pragma unroll
        for (int d = 1; d < 64; d <<= 1) {
            float y = __shfl_up(x, d, 64);
            if (tid >= d) x += y;
        }
        float g63 = __shfl(x, 63, 64);
        gs[tid] = x;
        bs[tid] = beb[(size_t)bh * L_ + c * 64 + tid];
        egq[tid] = expf(x);
        egk[tid] = expf(g63 - x);
    }
    // build KcT (raw k transposed) in LDS: 64 rows x 192 cols = 1536 groups of 8
    for (int cc = tid; cc < 1536; cc += 256) {
        int row = cc / 24, g8 = (cc % 24) * 8;
        short8 vv = *(const short8*)&k[qko + (size_t)row * QKLD + g8];
        #pragma unroll
        for (int e = 0; e < 8; ++e) KcT[(g8 + e) * 72 + row] = (ushort_t)vv[e];
    }

    // KK = K K^T, QK = Q K^T via MFMA (direct global frag loads)
    f32x4 kkf[4], qkf[4];
    #pragma unroll
    for (int nt = 0; nt < 4; ++nt) { kkf[nt] = (f32x4){0,0,0,0}; qkf[nt] = (f32x4){0,0,0,0}; }
    #pragma unroll
    for (int kk = 0; kk < 6; ++kk) {
        int k0 = kk * 32 + kg * 8;
        short8 aK = *(const short8*)&k[qko + (size_t)(16 * w + fr) * QKLD + k0];
        short8 aQ = *(const short8*)&q[qko + (size_t)(16 * w + fr) * QKLD + k0];
        #pragma unroll
        for (int nt = 0; nt < 4; ++nt) {
            short8 bK = *(const short8*)&k[qko + (size_t)(16 * nt + fr) * QKLD + k0];
            kkf[nt] = MFMA_(aK, bK, kkf[nt]);
            qkf[nt] = MFMA_(aQ, bK, qkf[nt]);
        }
    }
    __syncthreads();   // gs/bs/egq/egk + KcT ready; all raw q/k reads done

    // T and P  (clamp exponent: for s<=t it is provably <=0; kills spurious inf)
    #pragma unroll
    for (int nt = 0; nt < 4; ++nt)
        #pragma unroll
        for (int j = 0; j < 4; ++j) {
            int t = 16 * w + kg * 4 + j;
            int s = 16 * nt + fr;
            float dg = expf(fminf(gs[t] - gs[s], 0.f));
            Tm[t * 68 + s] = (s < t) ? bs[t] * dg * kkf[nt][j] : 0.f;
            float pv = (s <= t) ? dg * qkf[nt][j] : 0.f;
            pbuf[(size_t)cb * 4096 + t * 64 + s] = f2bf(pv);
        }
    // Q' in place: 64 rows x 192 cols = 1536 groups of 8
    for (int cc = tid; cc < 1536; cc += 256) {
        int row = cc / 24, g8 = (cc % 24) * 8;
        float eg = egq[row];
        ushort_t* p = &q[qko + (size_t)row * QKLD + g8];
        short8 vv = *(const short8*)p;
        short8 ov;
        #pragma unroll
        for (int e = 0; e < 8; ++e) ov[e] = (short)f2bf(bf2f((ushort_t)vv[e]) * eg);
        *(short8*)p = ov;
    }
    if (tid == 0) acb[cb] = egq[63];
    __syncthreads();   // Tm complete

    // triangular inverse: column j = lane, (I+T) x = e_j (wave 0)
    if (tid < 64) {
        float x[64];
        #pragma unroll
        for (int t = 0; t < 64; ++t) x[t] = (t == tid) ? 1.f : 0.f;
        #pragma unroll
        for (int s = 0; s < 63; ++s) {
            float xs_ = x[s];
            #pragma unroll
            for (int t = s + 1; t < 64; ++t)
                x[t] -= Tm[t * 68 + s] * xs_;
        }
        float bj = bs[tid], ej = egq[tid];
        #pragma unroll
        for (int t = 0; t < 64; ++t) {
            float mb = x[t] * bj;
            mbuf[(size_t)cb * 4096 + t * 64 + tid] = f2bf(mb);
            Mw[t * 72 + tid] = f2bf(mb * ej);
        }
    }
    __syncthreads();   // Mw ready

    // wneg = -(Mw @ K)  [64x192]
    f32x4 wf[12];
    #pragma unroll
    for (int nt = 0; nt < 12; ++nt) wf[nt] = (f32x4){0, 0, 0, 0};
    #pragma unroll
    for (int kk = 0; kk < 2; ++kk) {
        short8 aM = *(const short8*)&Mw[(16 * w + fr) * 72 + kk * 32 + kg * 8];
        #pragma unroll
        for (int nt = 0; nt < 12; ++nt) {
            short8 bT = *(const short8*)&KcT[(16 * nt + fr) * 72 + kk * 32 + kg * 8];
            wf[nt] = MFMA_(aM, bT, wf[nt]);
        }
    }
    #pragma unroll
    for (int nt = 0; nt < 12; ++nt)
        #pragma unroll
        for (int j = 0; j < 4; ++j) {
            int t = 16 * w + kg * 4 + j;
            wneg[(size_t)cb * 12288 + t * 192 + 16 * nt + fr] = f2bf(-wf[nt][j]);
        }
    // K''^T remap in place over k footprint: idx = dk*64 + s
    for (int cc = tid; cc < 1536; cc += 256) {
        int fi = cc * 8;
        int dk = fi >> 6, s = fi & 63;
        short8 ov;
        #pragma unroll
        for (int e = 0; e < 8; ++e)
            ov[e] = (short)f2bf(bf2f(KcT[dk * 72 + s + e]) * egk[s + e]);
        *(short8*)&k[qko + (size_t)(fi / 192) * QKLD + (fi % 192)] = ov;
    }
}

// Phase 2: 8 waves (512 thr). Waves 0-3 = producers (stage S, U, dS), waves
// 4-7 = consumers (O of previous chunk) on double-buffered Sb/Ub.
// SINGLE-buffered operand regs with early-issue reloads (R14 known-good).
struct POps { short8 m[2], w[6], v[2]; };
struct KOps { short8 kk[6]; float ac; };
struct QOps { short8 q[6], p[2]; };

__global__ __launch_bounds__(512, 1)
void k_p2(const ushort_t* __restrict__ qp, const ushort_t* __restrict__ k2,
          ushort_t* __restrict__ vo,
          const ushort_t* __restrict__ pbuf, const ushort_t* __restrict__ mbuf,
          const ushort_t* __restrict__ wneg, const float* __restrict__ acb) {
    __shared__ __align__(16) ushort_t Sb[2][48 * 200];   // [dv][dk] state copy
    __shared__ __align__(16) ushort_t Vb[48 * 72];       // [dv][s]
    __shared__ __align__(16) ushort_t Ub[2][48 * 72];    // [dv][s]
    const int tid = threadIdx.x;
    const int lane = tid & 63, wv = tid >> 6;
    const int fr = lane & 15, kg = lane >> 4;
    const int bx = blockIdx.x;
    const int sl = bx >> 5, bh = bx & 31;
    const int b = bh >> 2, h = bh & 3;
    const int dvb = h * DV_ + sl * 48;
    const bool prod = tid < 256;
    const int wc = wv - 4;                 // consumer wave idx 0..3
    const int vs = tid & 63, vdv8 = (tid >> 6) & 3;
    const bool hasv1 = tid < 128;

    f32x4 Sreg[3][3];   // producers: dk = 16*(3wv+mi)+kg*4+j, dv = 16nt+fr
    #pragma unroll
    for (int mi = 0; mi < 3; ++mi)
        #pragma unroll
        for (int nt = 0; nt < 3; ++nt) Sreg[mi][nt] = (f32x4){0, 0, 0, 0};

    POps po; KOps ko; QOps qo;

    auto loadV = [&](int c) {
        const int rb = b * L_ + c * 64;
        po.v[0] = *(const short8*)&vo[(size_t)(rb + vs) * VALDIM + dvb + vdv8 * 8];
        if (hasv1)
            po.v[1] = *(const short8*)&vo[(size_t)(rb + vs) * VALDIM + dvb + (vdv8 + 4) * 8];
    };
    auto loadMW = [&](int c) {
        const int cb = bh * 32 + c;
        const ushort_t* mA = mbuf + (size_t)cb * 4096 + (16 * wv + fr) * 64 + kg * 8;
        po.m[0] = *(const short8*)&mA[0];
        po.m[1] = *(const short8*)&mA[32];
        const ushort_t* wA = wneg + (size_t)cb * 12288 + (16 * wv + fr) * 192 + kg * 8;
        #pragma unroll
        for (int kk = 0; kk < 6; ++kk) po.w[kk] = *(const short8*)&wA[kk * 32];
    };
    auto loadKA = [&](int c) {
        const int cb = bh * 32 + c;
        const int rb = b * L_ + c * 64;
        #pragma unroll
        for (int mi = 0; mi < 3; ++mi)
            #pragma unroll
            for (int kk = 0; kk < 2; ++kk) {
                int idx = (16 * (3 * wv + mi) + fr) * 64 + kk * 32 + kg * 8;
                ko.kk[mi * 2 + kk] = *(const short8*)&k2[(size_t)(rb + idx / 192) * QKLD + h * DK_ + (idx % 192)];
            }
        ko.ac = acb[cb];
    };
    auto loadQP = [&](int c) {
        const int cb = bh * 32 + c;
        const int rb = b * L_ + c * 64;
        const ushort_t* qA = qp + (size_t)(rb + 16 * wc + fr) * QKLD + h * DK_ + kg * 8;
        #pragma unroll
        for (int kk = 0; kk < 6; ++kk) qo.q[kk] = *(const short8*)&qA[kk * 32];
        const ushort_t* pA = pbuf + (size_t)cb * 4096 + (16 * wc + fr) * 64 + kg * 8;
        qo.p[0] = *(const short8*)&pA[0];
        qo.p[1] = *(const short8*)&pA[32];
    };
    auto doO = [&](int prv, int rbp) {
        f32x4 of[3];
        #pragma unroll
        for (int nt = 0; nt < 3; ++nt) of[nt] = (f32x4){0, 0, 0, 0};
        #pragma unroll
        for (int kk = 0; kk < 6; ++kk)
            #pragma unroll
            for (int nt = 0; nt < 3; ++nt) {
                short8 bb_ = *(const short8*)&Sb[prv][(16 * nt + fr) * 200 + kk * 32 + kg * 8];
                of[nt] = MFMA_(qo.q[kk], bb_, of[nt]);
            }
        #pragma unroll
        for (int kk = 0; kk < 2; ++kk)
            #pragma unroll
            for (int nt = 0; nt < 3; ++nt) {
                short8 bb_ = *(const short8*)&Ub[prv][(16 * nt + fr) * 72 + kk * 32 + kg * 8];
                of[nt] = MFMA_(qo.p[kk], bb_, of[nt]);
            }
        #pragma unroll
        for (int nt = 0; nt < 3; ++nt)
            #pragma unroll
            for (int j = 0; j < 4; ++j)
                vo[(size_t)(rbp + 16 * wc + kg * 4 + j) * VALDIM + dvb + 16 * nt + fr] = f2bf(of[nt][j]);
    };

    // prologue
    if (prod) { loadV(0); loadMW(0); loadKA(0); }
    else      { loadQP(0); }

    #pragma unroll 1
    for (int c = 0; c < 32; ++c) {
        const int cur = c & 1, prv = cur ^ 1;
        const int rb = b * L_ + c * 64;

        // ---- phase A ----
        if (prod) {
            if (c > 0) {
                // dS_{c-1} = K''^T_{c-1} @ U_{c-1}; Sreg = ac*Sreg + dS (ko = chunk c-1)
                #pragma unroll
                for (int mi = 0; mi < 3; ++mi) {
                    f32x4 dsf[3];
                    #pragma unroll
                    for (int nt = 0; nt < 3; ++nt) dsf[nt] = (f32x4){0, 0, 0, 0};
                    #pragma unroll
                    for (int kk = 0; kk < 2; ++kk)
                        #pragma unroll
                        for (int nt = 0; nt < 3; ++nt) {
                            short8 bb_ = *(const short8*)&Ub[prv][(16 * nt + fr) * 72 + kk * 32 + kg * 8];
                            dsf[nt] = MFMA_(ko.kk[mi * 2 + kk], bb_, dsf[nt]);
                        }
                    #pragma unroll
                    for (int nt = 0; nt < 3; ++nt)
                        #pragma unroll
                        for (int j = 0; j < 4; ++j)
                            Sreg[mi][nt][j] = ko.ac * Sreg[mi][nt][j] + dsf[nt][j];
                }
                loadKA(c);   // ko dead; reload for use at A(c+1)
            }
            #pragma unroll
            for (int mi = 0; mi < 3; ++mi) {
                int dk = 16 * (3 * wv + mi) + kg * 4;
                #pragma unroll
                for (int nt = 0; nt < 3; ++nt) {
                    int dv = 16 * nt + fr;
                    ushort4v pk;
                    #pragma unroll
                    for (int j = 0; j < 4; ++j) pk[j] = f2bf(Sreg[mi][nt][j]);
                    *(ushort4v*)&Sb[cur][dv * 200 + dk] = pk;
                }
            }
            #pragma unroll
            for (int e = 0; e < 8; ++e) Vb[(vdv8 * 8 + e) * 72 + vs] = (ushort_t)po.v[0][e];
            if (hasv1) {
                #pragma unroll
                for (int e = 0; e < 8; ++e) Vb[((vdv8 + 4) * 8 + e) * 72 + vs] = (ushort_t)po.v[1][e];
            }
            if (c + 1 < 32) loadV(c + 1);   // po.v dead; reload for A(c+1)
        } else {
            if (c > 0) {
                doO(prv, rb - 64);          // uses qo = chunk c-1
                loadQP(c);                  // qo dead; reload for A(c+1)/epilogue
            }
        }
        asm volatile("s_waitcnt lgkmcnt(0)" ::: "memory");
        __builtin_amdgcn_s_barrier();

        // ---- phase B ----
        if (prod) {
            f32x4 uf[3];
            #pragma unroll
            for (int nt = 0; nt < 3; ++nt) uf[nt] = (f32x4){0, 0, 0, 0};
            #pragma unroll
            for (int kk = 0; kk < 2; ++kk)
                #pragma unroll
                for (int nt = 0; nt < 3; ++nt) {
                    short8 bb_ = *(const short8*)&Vb[(16 * nt + fr) * 72 + kk * 32 + kg * 8];
                    uf[nt] = MFMA_(po.m[kk], bb_, uf[nt]);
                }
            #pragma unroll
            for (int kk = 0; kk < 6; ++kk)
                #pragma unroll
                for (int nt = 0; nt < 3; ++nt) {
                    short8 bb_ = *(const short8*)&Sb[cur][(16 * nt + fr) * 200 + kk * 32 + kg * 8];
                    uf[nt] = MFMA_(po.w[kk], bb_, uf[nt]);
                }
            {
                int t = 16 * wv + kg * 4;
                #pragma unroll
                for (int nt = 0; nt < 3; ++nt) {
                    int dv = 16 * nt + fr;
                    ushort4v pk;
                    #pragma unroll
                    for (int j = 0; j < 4; ++j) pk[j] = f2bf(uf[nt][j]);
                    *(ushort4v*)&Ub[cur][dv * 72 + t] = pk;
                }
            }
            if (c + 1 < 32) loadMW(c + 1);  // po.m/w dead; reload for B(c+1)
        }
        asm volatile("s_waitcnt lgkmcnt(0)" ::: "memory");
        __builtin_amdgcn_s_barrier();
    }
    if (!prod) doO(1, b * L_ + 31 * 64);   // O_31 uses qo(31) loaded at A(31)
}

// ---------- per-head RMSNorm * swish-gate (in place on g) ----------
__global__ __launch_bounds__(256)
void k_rmsgate(const ushort_t* __restrict__ o, ushort_t* __restrict__ g,
               const float* __restrict__ gw) {
    const int w = threadIdx.x >> 6, lane = threadIdx.x & 63;
    const int idx = blockIdx.x * 4 + w;
    const int row = idx >> 2, h = idx & 3;
    const ushort_t* po = o + (size_t)row * VALDIM + h * DV_;
    ushort_t* pg = g + (size_t)row * VALDIM + h * DV_;
    float of[6], gf[6];
    float ss = 0.f;
    #pragma unroll
    for (int j = 0; j < 6; ++j) {
        int d = j * 64 + lane;
        of[j] = bf2f(po[d]); gf[j] = bf2f(pg[d]);
        ss += of[j] * of[j];
    }
    ss = wsum(ss);
    float rms = rsqrtf(ss * (1.f / 384.f) + 1e-5f);
    #pragma unroll
    for (int j = 0; j < 6; ++j) {
        int d = j * 64 + lane;
        float gv = gf[j];
        float val = of[j] * rms * gw[d] * (gv / (1.f + expf(-gv)));
        pg[d] = f2bf(val);
    }
}

// ---------- launch ----------
extern "C" void kernel_launch(void* const* d_in, const int* in_sizes, int n_in,
                              void* d_out, int out_size, void* d_ws, size_t ws_size,
                              hipStream_t stream) {
    const float* x    = (const float*)d_in[0];
    const float* Win  = (const float*)d_in[1];
    const float* cxw  = (const float*)d_in[2];
    const float* cxb  = (const float*)d_in[3];
    const float* czw  = (const float*)d_in[4];
    const float* czb  = (const float*)d_in[5];
    const float* Wq   = (const float*)d_in[6];
    const float* Wk   = (const float*)d_in[7];
    const float* Wv   = (const float*)d_in[8];
    const float* Wg   = (const float*)d_in[9];
    const float* Wgk  = (const float*)d_in[10];
    const float* Wb   = (const float*)d_in[11];
    const float* bb   = (const float*)d_in[12];
    const float* Alog = (const float*)d_in[13];
    const float* dtb  = (const float*)d_in[14];
    const float* gnw  = (const float*)d_in[15];
    const float* Wso  = (const float*)d_in[16];
    const float* Wout = (const float*)d_in[17];
    float* out = (float*)d_out;

    // ---- workspace layout (234,360,832 bytes) ----
    char* ws = (char*)d_ws;
    const size_t OFF_Q    = 0;
    const size_t OFF_P    = 50331648;
    const size_t OFF_MB   = 58720256;
    const size_t OFF_XS   = 67108864;
    const size_t OFF_ZS   = 100663296;
    const size_t OFF_VO   = 134217728;
    const size_t OFF_WNEG = 184549376;
    const size_t OFF_W    = 209715200;
    const size_t OFF_GK   = 233832448;
    const size_t OFF_BE   = 234094592;
    const size_t OFF_AC   = 234356736;
    const size_t NEEDED   = 234360832;

    if (ws_size < NEEDED) {
        k_zero_f32<<<(out_size + 255) / 256, 256, 0, stream>>>(out, out_size);
        return;
    }

    ushort_t* qkb     = (ushort_t*)(ws + OFF_Q);      // [M][1536] combined q|k
    ushort_t* pbuf    = (ushort_t*)(ws + OFF_P);
    ushort_t* mbuf    = (ushort_t*)(ws + OFF_MB);
    ushort_t* gbuf    = (ushort_t*)(ws + OFF_Q);      // overlays qk after p2
    ushort_t* xz      = (ushort_t*)(ws + OFF_Q);      // [M][2048] pre-conv
    ushort_t* xs      = (ushort_t*)(ws + OFF_XS);
    ushort_t* zs      = (ushort_t*)(ws + OFF_ZS);
    ushort_t* x_bf    = (ushort_t*)(ws + OFF_VO);
    ushort_t* vb      = (ushort_t*)(ws + OFF_VO);
    ushort_t* wneg    = (ushort_t*)(ws + OFF_WNEG);
    ushort_t* wInT    = (ushort_t*)(ws + OFF_W);                  // 4,194,304
    ushort_t* wQT     = (ushort_t*)(ws + OFF_W + 4194304);        // 1,572,864
    ushort_t* wKT     = (ushort_t*)(ws + OFF_W + 5767168);        // 1,572,864
    ushort_t* wVT     = (ushort_t*)(ws + OFF_W + 7340032);        // 3,145,728
    ushort_t* wGT     = (ushort_t*)(ws + OFF_W + 10485760);       // 3,145,728
    ushort_t* wSoBf   = (ushort_t*)(ws + OFF_W + 13631488);       // 3,145,728 [1536][1024]
    ushort_t* wOutTopT= (ushort_t*)(ws + OFF_W + 16777216);       // 2,097,152 [1024][1024]
    ushort_t* wBigT   = (ushort_t*)(ws + OFF_W + 18874368);       // 5,242,880 [1024][2560]
    float*    gkbuf   = (float*)(ws + OFF_GK);
    float*    bebuf   = (float*)(ws + OFF_BE);
    float*    acbuf   = (float*)(ws + OFF_AC);

    // P1. fused convert + all weight transposes (one dispatch)
    k_prep<<<17664, 256, 0, stream>>>(x, Win, Wq, Wk, Wv, Wg, Wso, Wout,
                                      x_bf, wInT, wQT, wKT, wVT, wGT,
                                      wSoBf, wOutTopT, wBigT);

    // P1.5. WcombT = Wso@Wout_top pre-association -> wBigT cols 0..1535
    k_gemm<1, 0><<<8 * (QKLD / 128), 256, 0, stream>>>(
        wOutTopT, nullptr, wSoBf, wBigT, QKLD, DMODEL, 0, DMODEL, 0, DMODEL, 2560);

    // P2. xz = x @ W_in
    k_gemm<1, 0><<<128 * (DINNER / 128), 256, 0, stream>>>(
        x_bf, nullptr, wInT, xz, DINNER, DMODEL, 0, DMODEL, 0, DMODEL, DINNER);

    // P3. dual depthwise conv + SiLU -> xs, zs (rolling window, 1 read/row)
    k_conv_silu<<<B_ * (L_ / CONV_LC), 256, 0, stream>>>(xz, cxw, cxb, czw, czb, xs, zs);

    // P4. gk / beta
    k_gkbeta<<<M_ / 4, 256, 0, stream>>>(xs, Wgk, Wb, bb, Alog, dtb, gkbuf, bebuf);

    // P5. fused q|k projection (N=1536) + v projection
    k_gemm<1, 0><<<128 * (QKLD / 128), 256, 0, stream>>>(
        xs, nullptr, wQT, qkb, QKLD, DSSM, 0, DSSM, 0, DSSM, QKLD);
    k_gemm<1, 0><<<128 * (VALDIM / 128), 256, 0, stream>>>(
        xs, nullptr, wVT, vb, VALDIM, DSSM, 0, DSSM, 0, DSSM, VALDIM);

    // P6. l2norm q|k (8 groups of 192 per row)
    k_l2norm<<<M_ * 2, 256, 0, stream>>>(qkb);

    // P7. chunked delta rule
    k_p1<<<1024, 256, 0, stream>>>(qkb, qkb + 768, gkbuf, bebuf, pbuf, mbuf, wneg, acbuf);
    k_p2<<<256, 512, 0, stream>>>(qkb, qkb + 768, vb, pbuf, mbuf, wneg, acbuf);

    // P8. g projection (over dead qk)
    k_gemm<1, 0><<<128 * (VALDIM / 128), 256, 0, stream>>>(
        xs, nullptr, wGT, gbuf, VALDIM, DSSM, 0, DSSM, 0, DSSM, VALDIM);

    // P9. RMSNorm * swish gate, in place on g (reads O from vb)
    k_rmsgate<<<M_, 256, 0, stream>>>(vb, gbuf, gnw);

    // P10. out = og @ Wcomb + zs @ Wout_bot  (DUAL-A, virtual K=2560, f32 out)
    k_gemm<0, 1><<<128 * (DMODEL / 128), 256, 0, stream>>>(
        gbuf, zs, wBigT, out, DMODEL, 2560, QKLD, QKLD, DSSM, 2560, DMODEL);
}

// Round 17
// 775.815 us; speedup vs baseline: 1.3337x; 1.3337x over previous
//
#include <hip/hip_runtime.h>

typedef unsigned short ushort_t;
typedef short short8 __attribute__((ext_vector_type(8)));
typedef float f32x4 __attribute__((ext_vector_type(4)));
typedef unsigned short ushort4v __attribute__((ext_vector_type(4)));

#define B_     8
#define L_     2048
#define DMODEL 1024
#define DINNER 2048
#define DSSM   1024
#define H_     4
#define DK_    192
#define DV_    384
#define KEYDIM 768
#define QKLD   1536   // combined q|k row stride
#define VALDIM 1536
#define M_     (B_ * L_)   // 16384

#define MFMA_(a,b,c) __builtin_amdgcn_mfma_f32_16x16x32_bf16(a, b, c, 0, 0, 0)

// ---------- helpers ----------
__device__ __forceinline__ float bf2f(ushort_t u) {
    return __uint_as_float(((unsigned)u) << 16);
}
__device__ __forceinline__ ushort_t f2bf(float f) {
    unsigned x = __float_as_uint(f);
    x += 0x7fffu + ((x >> 16) & 1u);   // RNE
    return (ushort_t)(x >> 16);
}
__device__ __forceinline__ float wsum(float x) {
    #pragma unroll
    for (int m = 1; m < 64; m <<= 1) x += __shfl_xor(x, m, 64);
    return x;
}
__device__ __forceinline__ void gload_lds16(const ushort_t* g, ushort_t* l) {
    __builtin_amdgcn_global_load_lds(
        (const __attribute__((address_space(1))) void*)g,
        (__attribute__((address_space(3))) void*)l, 16, 0, 0);
}

// ---------- zero d_out (fallback when ws too small) ----------
__global__ __launch_bounds__(256)
void k_zero_f32(float* __restrict__ out, int n) {
    int i = blockIdx.x * 256 + threadIdx.x;
    if (i < n) out[i] = 0.f;
}

// ---------- fused prep ----------
__global__ __launch_bounds__(256)
void k_prep(const float* __restrict__ x,
            const float* __restrict__ Win, const float* __restrict__ Wq,
            const float* __restrict__ Wk,  const float* __restrict__ Wv,
            const float* __restrict__ Wg,  const float* __restrict__ Wso,
            const float* __restrict__ Wout,
            ushort_t* __restrict__ x_bf,
            ushort_t* __restrict__ wInT, ushort_t* __restrict__ wQT,
            ushort_t* __restrict__ wKT,  ushort_t* __restrict__ wVT,
            ushort_t* __restrict__ wGT,  ushort_t* __restrict__ wSoBf,
            ushort_t* __restrict__ wOutTopT, ushort_t* __restrict__ wBigT) {
    __shared__ float tile[32][33];
    int id = blockIdx.x;
    if (id < 8192) {
        int i = id * 256 + threadIdx.x;
        const float4* p = (const float4*)(x + (size_t)i * 8);
        float4 a = p[0], b = p[1];
        ushort4v r0 = { f2bf(a.x), f2bf(a.y), f2bf(a.z), f2bf(a.w) };
        ushort4v r1 = { f2bf(b.x), f2bf(b.y), f2bf(b.z), f2bf(b.w) };
        ushort4v* o = (ushort4v*)(x_bf + (size_t)i * 8);
        o[0] = r0; o[1] = r1;
        return;
    }
    id -= 8192;
    if (id < 768) {   // Wso straight convert
        int i = id * 256 + threadIdx.x;
        const float4* p = (const float4*)(Wso + (size_t)i * 8);
        float4 a = p[0], b = p[1];
        ushort4v r0 = { f2bf(a.x), f2bf(a.y), f2bf(a.z), f2bf(a.w) };
        ushort4v r1 = { f2bf(b.x), f2bf(b.y), f2bf(b.z), f2bf(b.w) };
        ushort4v* o = (ushort4v*)(wSoBf + (size_t)i * 8);
        o[0] = r0; o[1] = r1;
        return;
    }
    id -= 768;
    const float* in; ushort_t* outp; int C, nbx, ldout;
    if (id < 2048)                { in = Win;            outp = wInT;        C = 2048; nbx = 64; ldout = 1024; }
    else if ((id -= 2048) < 768)  { in = Wq;             outp = wQT;         C = 768;  nbx = 24; ldout = 1024; }
    else if ((id -= 768) < 768)   { in = Wk;             outp = wKT;         C = 768;  nbx = 24; ldout = 1024; }
    else if ((id -= 768) < 1536)  { in = Wv;             outp = wVT;         C = 1536; nbx = 48; ldout = 1024; }
    else if ((id -= 1536) < 1536) { in = Wg;             outp = wGT;         C = 1536; nbx = 48; ldout = 1024; }
    else if ((id -= 1536) < 1024) { in = Wout;           outp = wOutTopT;    C = 1024; nbx = 32; ldout = 1024; }
    else { id -= 1024;              in = Wout + 1048576; outp = wBigT + 1536; C = 1024; nbx = 32; ldout = 2560; }
    int bx = id % nbx, by = id / nbx;
    int tx = threadIdx.x & 31, ty = threadIdx.x >> 5;   // 32x8
    int c0 = bx * 32, r0 = by * 32;
    #pragma unroll
    for (int i = 0; i < 32; i += 8)
        tile[ty + i][tx] = in[(size_t)(r0 + ty + i) * C + c0 + tx];
    __syncthreads();
    #pragma unroll
    for (int i = 0; i < 32; i += 8)
        outp[(size_t)(c0 + ty + i) * ldout + r0 + tx] = f2bf(tile[tx][ty + i]);
}

// ---------- GEMM: C[M,N] = A[M,K](bf16) * Bt[N,K](bf16), f32 accum ----------
// 128x128 tile, BK=32, TRIPLE-buffered LDS with counted vmcnt:
// per iter: vmcnt(4) -> s_barrier -> stage(t+2 -> buf (t+2)%3) -> compute(t).
// 1-D grid with XCD-grouped swizzle: id == by (mod 8).
// DUAL: virtual K = [A (K1) | A2 (K-K1)] for the fused output GEMM.
// SPLIT output: col-blocks bx >= NSPLIT write to Cv2 at col (n0 - NSPLIT*128).
template<int OUT_BF16, int DUAL>
__global__ __launch_bounds__(256)
void k_gemm(const ushort_t* __restrict__ A, const ushort_t* __restrict__ A2,
            const ushort_t* __restrict__ Bt, void* __restrict__ Cv, void* __restrict__ Cv2,
            int NSPLIT, int N, int K, int K1, int lda, int lda2, int ldb, int ldc) {
    __shared__ ushort_t As[3][4096];
    __shared__ ushort_t Bs[3][4096];
    const int t = threadIdx.x;
    const int lane = t & 63, w = t >> 6;
    const int nbx = N >> 7;
    const int id = blockIdx.x;
    const int by = (id & 7) + 8 * ((id >> 3) / nbx);
    const int bx = (id >> 3) % nbx;
    const int m0 = by << 7, n0 = bx << 7;
    const int wm = (w >> 1) << 6, wn = (w & 1) << 6;
    const int fr = lane & 15, kg = lane >> 4;

    f32x4 acc[4][4];
    #pragma unroll
    for (int i = 0; i < 4; ++i)
        #pragma unroll
        for (int j = 0; j < 4; ++j) acc[i][j] = (f32x4){0.f, 0.f, 0.f, 0.f};

    const int srow = t >> 2, scol = (t & 3) << 3;
    const ushort_t* a0 = A + (size_t)(m0 + srow) * lda + scol;
    const ushort_t* a1 = a0 + (size_t)64 * lda;
    const ushort_t* c0 = DUAL ? A2 + (size_t)(m0 + srow) * lda2 + scol : a0;
    const ushort_t* c1 = DUAL ? c0 + (size_t)64 * lda2 : a1;
    const ushort_t* b0 = Bt + (size_t)(n0 + srow) * ldb + scol;
    const ushort_t* b1 = b0 + (size_t)64 * ldb;
    const int lof0 = w * 512, lof1 = 2048 + w * 512;

    auto stage = [&](int buf, int kt) {
        if (!DUAL || kt < K1) {
            gload_lds16(a0 + kt, &As[buf][lof0]);
            gload_lds16(a1 + kt, &As[buf][lof1]);
        } else {
            gload_lds16(c0 + (kt - K1), &As[buf][lof0]);
            gload_lds16(c1 + (kt - K1), &As[buf][lof1]);
        }
        gload_lds16(b0 + kt, &Bs[buf][lof0]);
        gload_lds16(b1 + kt, &Bs[buf][lof1]);
    };
    auto compute = [&](int buf) {
        short8 af[4], bf_[4];
        #pragma unroll
        for (int mi = 0; mi < 4; ++mi)
            af[mi] = *(const short8*)&As[buf][(wm + mi * 16 + fr) * 32 + kg * 8];
        #pragma unroll
        for (int ni = 0; ni < 4; ++ni)
            bf_[ni] = *(const short8*)&Bs[buf][(wn + ni * 16 + fr) * 32 + kg * 8];
        #pragma unroll
        for (int mi = 0; mi < 4; ++mi)
            #pragma unroll
            for (int ni = 0; ni < 4; ++ni)
                acc[mi][ni] = MFMA_(af[mi], bf_[ni], acc[mi][ni]);
    };

    const int NT = K >> 5;
    stage(0, 0);
    if (NT > 1) stage(1, 32);
    int bsel = 0;
    for (int tt = 0; tt < NT; ++tt) {
        if (tt + 1 < NT) { asm volatile("s_waitcnt vmcnt(4)" ::: "memory"); }
        else             { asm volatile("s_waitcnt vmcnt(0)" ::: "memory"); }
        __builtin_amdgcn_s_barrier();
        if (tt + 2 < NT) {
            int nb = bsel + 2; if (nb >= 3) nb -= 3;
            stage(nb, (tt + 2) << 5);
        }
        compute(bsel);
        ++bsel; if (bsel == 3) bsel = 0;
    }

    void* Cuse = Cv;
    int ncol = n0;
    if (bx >= NSPLIT) { Cuse = Cv2; ncol = n0 - (NSPLIT << 7); }
    const int rbase = m0 + wm + (lane >> 4) * 4;
    const int cbase = ncol + wn + fr;
    #pragma unroll
    for (int mi = 0; mi < 4; ++mi)
        #pragma unroll
        for (int ni = 0; ni < 4; ++ni)
            #pragma unroll
            for (int j = 0; j < 4; ++j) {
                size_t off = (size_t)(rbase + mi * 16 + j) * ldc + cbase + ni * 16;
                if (OUT_BF16) ((ushort_t*)Cuse)[off] = f2bf(acc[mi][ni][j]);
                else          ((float*)Cuse)[off]    = acc[mi][ni][j];
            }
}

// ---------- depthwise conv (K=4, pad 1/2) + SiLU, rolling-window ----------
#define CONV_LC 16
__global__ __launch_bounds__(256)
void k_conv_silu(const ushort_t* __restrict__ xz,
                 const float* __restrict__ wx, const float* __restrict__ bx,
                 const float* __restrict__ wz, const float* __restrict__ bz,
                 ushort_t* __restrict__ xs, ushort_t* __restrict__ zs) {
    const int blk = blockIdx.x;
    const int b = blk / (L_ / CONV_LC), chunk = blk % (L_ / CONV_LC);
    const int l0 = chunk * CONV_LC;
    const int c4 = threadIdx.x * 4;
    const size_t rowb = (size_t)b * L_;

    float wxv[4][4], wzv[4][4], bxv[4], bzv[4];
    #pragma unroll
    for (int e = 0; e < 4; ++e) {
        bxv[e] = bx[c4 + e]; bzv[e] = bz[c4 + e];
        float4 w1 = *(const float4*)&wx[(c4 + e) * 4];
        float4 w2 = *(const float4*)&wz[(c4 + e) * 4];
        wxv[e][0] = w1.x; wxv[e][1] = w1.y; wxv[e][2] = w1.z; wxv[e][3] = w1.w;
        wzv[e][0] = w2.x; wzv[e][1] = w2.y; wzv[e][2] = w2.z; wzv[e][3] = w2.w;
    }

    auto ldrow = [&](int l, ushort4v& xv, ushort4v& zv) {
        if ((unsigned)l < (unsigned)L_) {
            const ushort_t* p = xz + (rowb + l) * DINNER;
            xv = *(const ushort4v*)&p[c4];
            zv = *(const ushort4v*)&p[1024 + c4];
        } else {
            xv = (ushort4v){0, 0, 0, 0};
            zv = (ushort4v){0, 0, 0, 0};
        }
    };

    ushort4v xa, xb_, xc, xd, za, zb_, zc, zd, xp, zp;
    ldrow(l0 - 1, xa, za);
    ldrow(l0,     xb_, zb_);
    ldrow(l0 + 1, xc, zc);
    ldrow(l0 + 2, xd, zd);

    #pragma unroll
    for (int i = 0; i < CONV_LC; ++i) {
        const int l = l0 + i;
        if (i < CONV_LC - 1) ldrow(l + 3, xp, zp);   // prefetch next window row
        ushort4v ox, oz;
        #pragma unroll
        for (int e = 0; e < 4; ++e) {
            float ax = bxv[e] + wxv[e][0] * bf2f(xa[e]) + wxv[e][1] * bf2f(xb_[e])
                               + wxv[e][2] * bf2f(xc[e]) + wxv[e][3] * bf2f(xd[e]);
            float az = bzv[e] + wzv[e][0] * bf2f(za[e]) + wzv[e][1] * bf2f(zb_[e])
                               + wzv[e][2] * bf2f(zc[e]) + wzv[e][3] * bf2f(zd[e]);
            ox[e] = f2bf(ax / (1.f + expf(-ax)));
            oz[e] = f2bf(az / (1.f + expf(-az)));
        }
        *(ushort4v*)&xs[(rowb + l) * DSSM + c4] = ox;
        *(ushort4v*)&zs[(rowb + l) * DSSM + c4] = oz;
        xa = xb_; xb_ = xc; xc = xd; xd = xp;
        za = zb_; zb_ = zc; zc = zd; zd = zp;
    }
}

// ---------- gk / beta ----------
__global__ __launch_bounds__(256)
void k_gkbeta(const ushort_t* __restrict__ xs, const float* __restrict__ Wgk,
              const float* __restrict__ Wb, const float* __restrict__ bb,
              const float* __restrict__ Alog, const float* __restrict__ dtb,
              float* __restrict__ gk, float* __restrict__ beta) {
    const int w = threadIdx.x >> 6, lane = threadIdx.x & 63;
    const int row = blockIdx.x * 4 + w;
    const ushort_t* xr = xs + (size_t)row * DSSM + lane * 16;
    float sg[4] = {0, 0, 0, 0}, sb[4] = {0, 0, 0, 0};
    #pragma unroll
    for (int i = 0; i < 16; ++i) {
        float xv = bf2f(xr[i]);
        int kk = lane * 16 + i;
        float4 wg  = *(const float4*)&Wgk[kk * 4];
        float4 wb2 = *(const float4*)&Wb[kk * 4];
        sg[0] += xv * wg.x;  sg[1] += xv * wg.y;  sg[2] += xv * wg.z;  sg[3] += xv * wg.w;
        sb[0] += xv * wb2.x; sb[1] += xv * wb2.y; sb[2] += xv * wb2.z; sb[3] += xv * wb2.w;
    }
    #pragma unroll
    for (int h = 0; h < 4; ++h) { sg[h] = wsum(sg[h]); sb[h] = wsum(sb[h]); }
    if (lane < 4) {
        int h = lane;
        int b = row >> 11, l = row & (L_ - 1);
        float xgk = sg[h] + dtb[h];
        float sp = (xgk > 20.f) ? xgk : log1pf(expf(xgk));
        gk[(size_t)(b * 4 + h) * L_ + l] = -expf(Alog[h]) * sp;
        float xb = sb[h] + bb[h];
        beta[(size_t)(b * 4 + h) * L_ + l] = 1.f / (1.f + expf(-xb));
    }
}

// ---------- in-place l2norm over 192-wide groups of qk[M][1536] ----------
__global__ __launch_bounds__(256)
void k_l2norm(ushort_t* __restrict__ x) {
    const int w = threadIdx.x >> 6, lane = threadIdx.x & 63;
    const int idx = blockIdx.x * 4 + w;   // row*8 + group
    const int row = idx >> 3, g = idx & 7;
    ushort_t* p = x + (size_t)row * QKLD + g * DK_;
    float ss = 0.f;
    ushort4v v = {0, 0, 0, 0};
    if (lane < 48) {
        v = *(const ushort4v*)&p[lane * 4];
        #pragma unroll
        for (int e = 0; e < 4; ++e) { float f = bf2f(v[e]); ss += f * f; }
    }
    ss = wsum(ss);
    float r = rsqrtf(ss + 1e-6f);
    if (lane < 48) {
        ushort4v o;
        #pragma unroll
        for (int e = 0; e < 4; ++e) o[e] = f2bf(bf2f(v[e]) * r);
        *(ushort4v*)&p[lane * 4] = o;
    }
}

// ================== chunked gated delta rule ==================
__global__ __launch_bounds__(256)
void k_p1(ushort_t* __restrict__ q, ushort_t* __restrict__ k,
          const float* __restrict__ gkb, const float* __restrict__ beb,
          ushort_t* __restrict__ pbuf, ushort_t* __restrict__ mbuf,
          ushort_t* __restrict__ wneg, float* __restrict__ acb) {
    __shared__ ushort_t KcT[192 * 72];   // [dk][s] raw k transposed
    __shared__ float    Tm[64 * 68];
    __shared__ ushort_t Mw[64 * 72];     // Minv * beta_s * exp(g_s), bf16
    __shared__ float gs[64], bs[64], egq[64], egk[64];

    const int tid = threadIdx.x;
    const int lane = tid & 63, w = tid >> 6;
    const int fr = lane & 15, kg = lane >> 4;
    const int cb = blockIdx.x;           // bh*32 + c
    const int bh = cb >> 5, c = cb & 31;
    const int b = bh >> 2, h = bh & 3;
    const int rb = b * L_ + c * 64;
    const size_t qko = (size_t)rb * QKLD + h * DK_;

    // prefix sums + per-row scale factors (wave 0)
    if (tid < 64) {
        float x = gkb[(size_t)bh * L_ + c * 64 + tid];
        #pragma unroll
        for (int d = 1; d < 64; d <<= 1) {
            float y = __shfl_up(x, d, 64);
            if (tid >= d) x += y;
        }
        float g63 = __shfl(x, 63, 64);
        gs[tid] = x;
        bs[tid] = beb[(size_t)bh * L_ + c * 64 + tid];
        egq[tid] = expf(x);
        egk[tid] = expf(g63 - x);
    }
    // build KcT (raw k transposed) in LDS: 64 rows x 192 cols = 1536 groups of 8
    for (int cc = tid; cc < 1536; cc += 256) {
        int row = cc / 24, g8 = (cc % 24) * 8;
        short8 vv = *(const short8*)&k[qko + (size_t)row * QKLD + g8];
        #pragma unroll
        for (int e = 0; e < 8; ++e) KcT[(g8 + e) * 72 + row] = (ushort_t)vv[e];
    }

    // KK = K K^T, QK = Q K^T via MFMA (direct global frag loads)
    f32x4 kkf[4], qkf[4];
    #pragma unroll
    for (int nt = 0; nt < 4; ++nt) { kkf[nt] = (f32x4){0,0,0,0}; qkf[nt] = (f32x4){0,0,0,0}; }
    #pragma unroll
    for (int kk = 0; kk < 6; ++kk) {
        int k0 = kk * 32 + kg * 8;
        short8 aK = *(const short8*)&k[qko + (size_t)(16 * w + fr) * QKLD + k0];
        short8 aQ = *(const short8*)&q[qko + (size_t)(16 * w + fr) * QKLD + k0];
        #pragma unroll
        for (int nt = 0; nt < 4; ++nt) {
            short8 bK = *(const short8*)&k[qko + (size_t)(16 * nt + fr) * QKLD + k0];
            kkf[nt] = MFMA_(aK, bK, kkf[nt]);
            qkf[nt] = MFMA_(aQ, bK, qkf[nt]);
        }
    }
    __syncthreads();   // gs/bs/egq/egk + KcT ready; all raw q/k reads done

    // T and P  (clamp exponent: for s<=t it is provably <=0; kills spurious inf)
    #pragma unroll
    for (int nt = 0; nt < 4; ++nt)
        #pragma unroll
        for (int j = 0; j < 4; ++j) {
            int t = 16 * w + kg * 4 + j;
            int s = 16 * nt + fr;
            float dg = expf(fminf(gs[t] - gs[s], 0.f));
            Tm[t * 68 + s] = (s < t) ? bs[t] * dg * kkf[nt][j] : 0.f;
            float pv = (s <= t) ? dg * qkf[nt][j] : 0.f;
            pbuf[(size_t)cb * 4096 + t * 64 + s] = f2bf(pv);
        }
    // Q' in place: 64 rows x 192 cols = 1536 groups of 8
    for (int cc = tid; cc < 1536; cc += 256) {
        int row = cc / 24, g8 = (cc % 24) * 8;
        float eg = egq[row];
        ushort_t* p = &q[qko + (size_t)row * QKLD + g8];
        short8 vv = *(const short8*)p;
        short8 ov;
        #pragma unroll
        for (int e = 0; e < 8; ++e) ov[e] = (short)f2bf(bf2f((ushort_t)vv[e]) * eg);
        *(short8*)p = ov;
    }
    if (tid == 0) acb[cb] = egq[63];
    __syncthreads();   // Tm complete

    // triangular inverse: column j = lane, (I+T) x = e_j (wave 0)
    if (tid < 64) {
        float x[64];
        #pragma unroll
        for (int t = 0; t < 64; ++t) x[t] = (t == tid) ? 1.f : 0.f;
        #pragma unroll
        for (int s = 0; s < 63; ++s) {
            float xs_ = x[s];
            #pragma unroll
            for (int t = s + 1; t < 64; ++t)
                x[t] -= Tm[t * 68 + s] * xs_;
        }
        float bj = bs[tid], ej = egq[tid];
        #pragma unroll
        for (int t = 0; t < 64; ++t) {
            float mb = x[t] * bj;
            mbuf[(size_t)cb * 4096 + t * 64 + tid] = f2bf(mb);
            Mw[t * 72 + tid] = f2bf(mb * ej);
        }
    }
    __syncthreads();   // Mw ready

    // wneg = -(Mw @ K)  [64x192]
    f32x4 wf[12];
    #pragma unroll
    for (int nt = 0; nt < 12; ++nt) wf[nt] = (f32x4){0, 0, 0, 0};
    #pragma unroll
    for (int kk = 0; kk < 2; ++kk) {
        short8 aM = *(const short8*)&Mw[(16 * w + fr) * 72 + kk * 32 + kg * 8];
        #pragma unroll
        for (int nt = 0; nt < 12; ++nt) {
            short8 bT = *(const short8*)&KcT[(16 * nt + fr) * 72 + kk * 32 + kg * 8];
            wf[nt] = MFMA_(aM, bT, wf[nt]);
        }
    }
    #pragma unroll
    for (int nt = 0; nt < 12; ++nt)
        #pragma unroll
        for (int j = 0; j < 4; ++j) {
            int t = 16 * w + kg * 4 + j;
            wneg[(size_t)cb * 12288 + t * 192 + 16 * nt + fr] = f2bf(-wf[nt][j]);
        }
    // K''^T remap in place over k footprint: idx = dk*64 + s
    for (int cc = tid; cc < 1536; cc += 256) {
        int fi = cc * 8;
        int dk = fi >> 6, s = fi & 63;
        short8 ov;
        #pragma unroll
        for (int e = 0; e < 8; ++e)
            ov[e] = (short)f2bf(bf2f(KcT[dk * 72 + s + e]) * egk[s + e]);
        *(short8*)&k[qko + (size_t)(fi / 192) * QKLD + (fi % 192)] = ov;
    }
}

// Phase 2: 8 waves (512 thr). Waves 0-3 = producers (stage S, U, dS), waves
// 4-7 = consumers (O of previous chunk) on double-buffered Sb/Ub.
// SINGLE-buffered operand regs with early-issue reloads (R14 known-good).
struct POps { short8 m[2], w[6], v[2]; };
struct KOps { short8 kk[6]; float ac; };
struct QOps { short8 q[6], p[2]; };

__global__ __launch_bounds__(512, 1)
void k_p2(const ushort_t* __restrict__ qp, const ushort_t* __restrict__ k2,
          ushort_t* __restrict__ vo,
          const ushort_t* __restrict__ pbuf, const ushort_t* __restrict__ mbuf,
          const ushort_t* __restrict__ wneg, const float* __restrict__ acb) {
    __shared__ __align__(16) ushort_t Sb[2][48 * 200];   // [dv][dk] state copy
    __shared__ __align__(16) ushort_t Vb[48 * 72];       // [dv][s]
    __shared__ __align__(16) ushort_t Ub[2][48 * 72];    // [dv][s]
    const int tid = threadIdx.x;
    const int lane = tid & 63, wv = tid >> 6;
    const int fr = lane & 15, kg = lane >> 4;
    const int bx = blockIdx.x;
    const int sl = bx >> 5, bh = bx & 31;
    const int b = bh >> 2, h = bh & 3;
    const int dvb = h * DV_ + sl * 48;
    const bool prod = tid < 256;
    const int wc = wv - 4;                 // consumer wave idx 0..3
    const int vs = tid & 63, vdv8 = (tid >> 6) & 3;
    const bool hasv1 = tid < 128;

    f32x4 Sreg[3][3];   // producers: dk = 16*(3wv+mi)+kg*4+j, dv = 16nt+fr
    #pragma unroll
    for (int mi = 0; mi < 3; ++mi)
        #pragma unroll
        for (int nt = 0; nt < 3; ++nt) Sreg[mi][nt] = (f32x4){0, 0, 0, 0};

    POps po; KOps ko; QOps qo;

    auto loadV = [&](int c) {
        const int rb = b * L_ + c * 64;
        po.v[0] = *(const short8*)&vo[(size_t)(rb + vs) * VALDIM + dvb + vdv8 * 8];
        if (hasv1)
            po.v[1] = *(const short8*)&vo[(size_t)(rb + vs) * VALDIM + dvb + (vdv8 + 4) * 8];
    };
    auto loadMW = [&](int c) {
        const int cb = bh * 32 + c;
        const ushort_t* mA = mbuf + (size_t)cb * 4096 + (16 * wv + fr) * 64 + kg * 8;
        po.m[0] = *(const short8*)&mA[0];
        po.m[1] = *(const short8*)&mA[32];
        const ushort_t* wA = wneg + (size_t)cb * 12288 + (16 * wv + fr) * 192 + kg * 8;
        #pragma unroll
        for (int kk = 0; kk < 6; ++kk) po.w[kk] = *(const short8*)&wA[kk * 32];
    };
    auto loadKA = [&](int c) {
        const int cb = bh * 32 + c;
        const int rb = b * L_ + c * 64;
        #pragma unroll
        for (int mi = 0; mi < 3; ++mi)
            #pragma unroll
            for (int kk = 0; kk < 2; ++kk) {
                int idx = (16 * (3 * wv + mi) + fr) * 64 + kk * 32 + kg * 8;
                ko.kk[mi * 2 + kk] = *(const short8*)&k2[(size_t)(rb + idx / 192) * QKLD + h * DK_ + (idx % 192)];
            }
        ko.ac = acb[cb];
    };
    auto loadQP = [&](int c) {
        const int cb = bh * 32 + c;
        const int rb = b * L_ + c * 64;
        const ushort_t* qA = qp + (size_t)(rb + 16 * wc + fr) * QKLD + h * DK_ + kg * 8;
        #pragma unroll
        for (int kk = 0; kk < 6; ++kk) qo.q[kk] = *(const short8*)&qA[kk * 32];
        const ushort_t* pA = pbuf + (size_t)cb * 4096 + (16 * wc + fr) * 64 + kg * 8;
        qo.p[0] = *(const short8*)&pA[0];
        qo.p[1] = *(const short8*)&pA[32];
    };
    auto doO = [&](int prv, int rbp) {
        f32x4 of[3];
        #pragma unroll
        for (int nt = 0; nt < 3; ++nt) of[nt] = (f32x4){0, 0, 0, 0};
        #pragma unroll
        for (int kk = 0; kk < 6; ++kk)
            #pragma unroll
            for (int nt = 0; nt < 3; ++nt) {
                short8 bb_ = *(const short8*)&Sb[prv][(16 * nt + fr) * 200 + kk * 32 + kg * 8];
                of[nt] = MFMA_(qo.q[kk], bb_, of[nt]);
            }
        #pragma unroll
        for (int kk = 0; kk < 2; ++kk)
            #pragma unroll
            for (int nt = 0; nt < 3; ++nt) {
                short8 bb_ = *(const short8*)&Ub[prv][(16 * nt + fr) * 72 + kk * 32 + kg * 8];
                of[nt] = MFMA_(qo.p[kk], bb_, of[nt]);
            }
        #pragma unroll
        for (int nt = 0; nt < 3; ++nt)
            #pragma unroll
            for (int j = 0; j < 4; ++j)
                vo[(size_t)(rbp + 16 * wc + kg * 4 + j) * VALDIM + dvb + 16 * nt + fr] = f2bf(of[nt][j]);
    };

    // prologue
    if (prod) { loadV(0); loadMW(0); loadKA(0); }
    else      { loadQP(0); }

    #pragma unroll 1
    for (int c = 0; c < 32; ++c) {
        const int cur = c & 1, prv = cur ^ 1;
        const int rb = b * L_ + c * 64;

        // ---- phase A ----
        if (prod) {
            if (c > 0) {
                // dS_{c-1} = K''^T_{c-1} @ U_{c-1}; Sreg = ac*Sreg + dS (ko = chunk c-1)
                #pragma unroll
                for (int mi = 0; mi < 3; ++mi) {
                    f32x4 dsf[3];
                    #pragma unroll
                    for (int nt = 0; nt < 3; ++nt) dsf[nt] = (f32x4){0, 0, 0, 0};
                    #pragma unroll
                    for (int kk = 0; kk < 2; ++kk)
                        #pragma unroll
                        for (int nt = 0; nt < 3; ++nt) {
                            short8 bb_ = *(const short8*)&Ub[prv][(16 * nt + fr) * 72 + kk * 32 + kg * 8];
                            dsf[nt] = MFMA_(ko.kk[mi * 2 + kk], bb_, dsf[nt]);
                        }
                    #pragma unroll
                    for (int nt = 0; nt < 3; ++nt)
                        #pragma unroll
                        for (int j = 0; j < 4; ++j)
                            Sreg[mi][nt][j] = ko.ac * Sreg[mi][nt][j] + dsf[nt][j];
                }
                loadKA(c);   // ko dead; reload for use at A(c+1)
            }
            #pragma unroll
            for (int mi = 0; mi < 3; ++mi) {
                int dk = 16 * (3 * wv + mi) + kg * 4;
                #pragma unroll
                for (int nt = 0; nt < 3; ++nt) {
                    int dv = 16 * nt + fr;
                    ushort4v pk;
                    #pragma unroll
                    for (int j = 0; j < 4; ++j) pk[j] = f2bf(Sreg[mi][nt][j]);
                    *(ushort4v*)&Sb[cur][dv * 200 + dk] = pk;
                }
            }
            #pragma unroll
            for (int e = 0; e < 8; ++e) Vb[(vdv8 * 8 + e) * 72 + vs] = (ushort_t)po.v[0][e];
            if (hasv1) {
                #pragma unroll
                for (int e = 0; e < 8; ++e) Vb[((vdv8 + 4) * 8 + e) * 72 + vs] = (ushort_t)po.v[1][e];
            }
            if (c + 1 < 32) loadV(c + 1);   // po.v dead; reload for A(c+1)
        } else {
            if (c > 0) {
                doO(prv, rb - 64);          // uses qo = chunk c-1
                loadQP(c);                  // qo dead; reload for A(c+1)/epilogue
            }
        }
        asm volatile("s_waitcnt lgkmcnt(0)" ::: "memory");
        __builtin_amdgcn_s_barrier();

        // ---- phase B ----
        if (prod) {
            f32x4 uf[3];
            #pragma unroll
            for (int nt = 0; nt < 3; ++nt) uf[nt] = (f32x4){0, 0, 0, 0};
            #pragma unroll
            for (int kk = 0; kk < 2; ++kk)
                #pragma unroll
                for (int nt = 0; nt < 3; ++nt) {
                    short8 bb_ = *(const short8*)&Vb[(16 * nt + fr) * 72 + kk * 32 + kg * 8];
                    uf[nt] = MFMA_(po.m[kk], bb_, uf[nt]);
                }
            #pragma unroll
            for (int kk = 0; kk < 6; ++kk)
                #pragma unroll
                for (int nt = 0; nt < 3; ++nt) {
                    short8 bb_ = *(const short8*)&Sb[cur][(16 * nt + fr) * 200 + kk * 32 + kg * 8];
                    uf[nt] = MFMA_(po.w[kk], bb_, uf[nt]);
                }
            {
                int t = 16 * wv + kg * 4;
                #pragma unroll
                for (int nt = 0; nt < 3; ++nt) {
                    int dv = 16 * nt + fr;
                    ushort4v pk;
                    #pragma unroll
                    for (int j = 0; j < 4; ++j) pk[j] = f2bf(uf[nt][j]);
                    *(ushort4v*)&Ub[cur][dv * 72 + t] = pk;
                }
            }
            if (c + 1 < 32) loadMW(c + 1);  // po.m/w dead; reload for B(c+1)
        }
        asm volatile("s_waitcnt lgkmcnt(0)" ::: "memory");
        __builtin_amdgcn_s_barrier();
    }
    if (!prod) doO(1, b * L_ + 31 * 64);   // O_31 uses qo(31) loaded at A(31)
}

// ---------- per-head RMSNorm * swish-gate (in place on g) ----------
__global__ __launch_bounds__(256)
void k_rmsgate(const ushort_t* __restrict__ o, ushort_t* __restrict__ g,
               const float* __restrict__ gw) {
    const int w = threadIdx.x >> 6, lane = threadIdx.x & 63;
    const int idx = blockIdx.x * 4 + w;
    const int row = idx >> 2, h = idx & 3;
    const ushort_t* po = o + (size_t)row * VALDIM + h * DV_;
    ushort_t* pg = g + (size_t)row * VALDIM + h * DV_;
    float of[6], gf[6];
    float ss = 0.f;
    #pragma unroll
    for (int j = 0; j < 6; ++j) {
        int d = j * 64 + lane;
        of[j] = bf2f(po[d]); gf[j] = bf2f(pg[d]);
        ss += of[j] * of[j];
    }
    ss = wsum(ss);
    float rms = rsqrtf(ss * (1.f / 384.f) + 1e-5f);
    #pragma unroll
    for (int j = 0; j < 6; ++j) {
        int d = j * 64 + lane;
        float gv = gf[j];
        float val = of[j] * rms * gw[d] * (gv / (1.f + expf(-gv)));
        pg[d] = f2bf(val);
    }
}

// ---------- launch ----------
extern "C" void kernel_launch(void* const* d_in, const int* in_sizes, int n_in,
                              void* d_out, int out_size, void* d_ws, size_t ws_size,
                              hipStream_t stream) {
    const float* x    = (const float*)d_in[0];
    const float* Win  = (const float*)d_in[1];
    const float* cxw  = (const float*)d_in[2];
    const float* cxb  = (const float*)d_in[3];
    const float* czw  = (const float*)d_in[4];
    const float* czb  = (const float*)d_in[5];
    const float* Wq   = (const float*)d_in[6];
    const float* Wk   = (const float*)d_in[7];
    const float* Wv   = (const float*)d_in[8];
    const float* Wg   = (const float*)d_in[9];
    const float* Wgk  = (const float*)d_in[10];
    const float* Wb   = (const float*)d_in[11];
    const float* bb   = (const float*)d_in[12];
    const float* Alog = (const float*)d_in[13];
    const float* dtb  = (const float*)d_in[14];
    const float* gnw  = (const float*)d_in[15];
    const float* Wso  = (const float*)d_in[16];
    const float* Wout = (const float*)d_in[17];
    float* out = (float*)d_out;

    // ---- workspace layout (234,360,832 bytes) ----
    char* ws = (char*)d_ws;
    const size_t OFF_Q    = 0;
    const size_t OFF_P    = 50331648;
    const size_t OFF_MB   = 58720256;
    const size_t OFF_XS   = 67108864;
    const size_t OFF_ZS   = 100663296;
    const size_t OFF_VO   = 134217728;
    const size_t OFF_WNEG = 184549376;
    const size_t OFF_W    = 209715200;
    const size_t OFF_GK   = 233832448;
    const size_t OFF_BE   = 234094592;
    const size_t OFF_AC   = 234356736;
    const size_t NEEDED   = 234360832;

    if (ws_size < NEEDED) {
        k_zero_f32<<<(out_size + 255) / 256, 256, 0, stream>>>(out, out_size);
        return;
    }

    ushort_t* qkb     = (ushort_t*)(ws + OFF_Q);      // [M][1536] combined q|k
    ushort_t* pbuf    = (ushort_t*)(ws + OFF_P);
    ushort_t* mbuf    = (ushort_t*)(ws + OFF_MB);
    ushort_t* gbuf    = (ushort_t*)(ws + OFF_Q);      // overlays qk after p2
    ushort_t* xz      = (ushort_t*)(ws + OFF_Q);      // [M][2048] pre-conv
    ushort_t* xs      = (ushort_t*)(ws + OFF_XS);
    ushort_t* zs      = (ushort_t*)(ws + OFF_ZS);
    ushort_t* x_bf    = (ushort_t*)(ws + OFF_VO);
    ushort_t* vb      = (ushort_t*)(ws + OFF_VO);
    ushort_t* wneg    = (ushort_t*)(ws + OFF_WNEG);
    ushort_t* wInT    = (ushort_t*)(ws + OFF_W);                  // 4,194,304
    ushort_t* wQT     = (ushort_t*)(ws + OFF_W + 4194304);        // 1,572,864 [768][1024]
    ushort_t* wKT     = (ushort_t*)(ws + OFF_W + 5767168);        // 1,572,864 (contiguous)
    ushort_t* wVT     = (ushort_t*)(ws + OFF_W + 7340032);        // 3,145,728 (contiguous)
    ushort_t* wGT     = (ushort_t*)(ws + OFF_W + 10485760);       // 3,145,728
    ushort_t* wSoBf   = (ushort_t*)(ws + OFF_W + 13631488);       // 3,145,728 [1536][1024]
    ushort_t* wOutTopT= (ushort_t*)(ws + OFF_W + 16777216);       // 2,097,152 [1024][1024]
    ushort_t* wBigT   = (ushort_t*)(ws + OFF_W + 18874368);       // 5,242,880 [1024][2560]
    float*    gkbuf   = (float*)(ws + OFF_GK);
    float*    bebuf   = (float*)(ws + OFF_BE);
    float*    acbuf   = (float*)(ws + OFF_AC);

    // P1. fused convert + all weight transposes (one dispatch)
    k_prep<<<17664, 256, 0, stream>>>(x, Win, Wq, Wk, Wv, Wg, Wso, Wout,
                                      x_bf, wInT, wQT, wKT, wVT, wGT,
                                      wSoBf, wOutTopT, wBigT);

    // P1.5. WcombT = Wso@Wout_top pre-association -> wBigT cols 0..1535
    k_gemm<1, 0><<<8 * (QKLD / 128), 256, 0, stream>>>(
        wOutTopT, nullptr, wSoBf, wBigT, nullptr, 9999,
        QKLD, DMODEL, 0, DMODEL, 0, DMODEL, 2560);

    // P2. xz = x @ W_in
    k_gemm<1, 0><<<128 * (DINNER / 128), 256, 0, stream>>>(
        x_bf, nullptr, wInT, xz, nullptr, 9999,
        DINNER, DMODEL, 0, DMODEL, 0, DMODEL, DINNER);

    // P3. dual depthwise conv + SiLU -> xs, zs (rolling window, 1 read/row)
    k_conv_silu<<<B_ * (L_ / CONV_LC), 256, 0, stream>>>(xz, cxw, cxb, czw, czb, xs, zs);

    // P4. gk / beta
    k_gkbeta<<<M_ / 4, 256, 0, stream>>>(xs, Wgk, Wb, bb, Alog, dtb, gkbuf, bebuf);

    // P5. merged q|k|v projection (N=3072, B = [wQT;wKT;wVT] contiguous):
    //     col-blocks 0..11 -> qkb, 12..23 -> vb (both ldc 1536)
    k_gemm<1, 0><<<128 * 24, 256, 0, stream>>>(
        xs, nullptr, wQT, qkb, vb, 12,
        3072, DSSM, 0, DSSM, 0, DSSM, QKLD);

    // P6. l2norm q|k (8 groups of 192 per row)
    k_l2norm<<<M_ * 2, 256, 0, stream>>>(qkb);

    // P7. chunked delta rule
    k_p1<<<1024, 256, 0, stream>>>(qkb, qkb + 768, gkbuf, bebuf, pbuf, mbuf, wneg, acbuf);
    k_p2<<<256, 512, 0, stream>>>(qkb, qkb + 768, vb, pbuf, mbuf, wneg, acbuf);

    // P8. g projection (over dead qk)
    k_gemm<1, 0><<<128 * (VALDIM / 128), 256, 0, stream>>>(
        xs, nullptr, wGT, gbuf, nullptr, 9999,
        VALDIM, DSSM, 0, DSSM, 0, DSSM, VALDIM);

    // P9. RMSNorm * swish gate, in place on g (reads O from vb)
    k_rmsgate<<<M_, 256, 0, stream>>>(vb, gbuf, gnw);

    // P10. out = og @ Wcomb + zs @ Wout_bot  (DUAL-A, virtual K=2560, f32 out)
    k_gemm<0, 1><<<128 * (DMODEL / 128), 256, 0, stream>>>(
        gbuf, zs, wBigT, out, nullptr, 9999,
        DMODEL, 2560, QKLD, QKLD, DSSM, 2560, DMODEL);
}